// Round 7
// baseline (192.658 us; speedup 1.0000x reference)
//
#include <hip/hip_runtime.h>
#include <cfloat>
#include <cmath>

#define NPTS 131072
#define NC   512
#define NREP 8
#define LOG2E 1.44269504088896340736f
#define LN2   0.69314718055994530942f

// v_exp_f32 computes 2^x; v_log_f32 computes log2(x). Raw builtins avoid the
// glibc __exp2f/__log2f macro collision (R5 compile failure).
__device__ __forceinline__ float fexp2(float x) { return __builtin_amdgcn_exp2f(x); }
__device__ __forceinline__ float flog2(float x) { return __builtin_amdgcn_logf(x); }

// ws float-index layout:
//  PM4  [0, 2048)       : per-comp float4 LOG2-domain (2k*mu, log2e*w - |mu|^2*k), k=log2e/(2s^2)
//  PQ4  [2048, 4096)    : per-comp float4 (mu_new[3], A_c)  [A in ln units]
//  ST   [4096, 20480)   : NREP replicas x 512 comps x float4 (Tx,Ty,Tz,S)
//  MISC [20480, 20488)  : [0]=sum|x|^2, [1]=inv2s2_new, [3]=sum gamma*lgamma (log2 units)
// z_n staged in d_out[3n] (k_estep writes, k_final reads then overwrites).
#define PM4_OFF  0
#define PQ4_OFF  2048
#define ST_OFF   4096
#define MISC_OFF (ST_OFF + NREP * NC * 4)

__device__ __forceinline__ float waveSum(float v) {
#pragma unroll
  for (int off = 32; off > 0; off >>= 1) v += __shfl_down(v, off, 64);
  return v;
}
__device__ __forceinline__ float waveMax(float v) {
#pragma unroll
  for (int off = 32; off > 0; off >>= 1) v = fmaxf(v, __shfl_down(v, off, 64));
  return v;
}

// ---------------------------------------------------------------------------
// Prep: fold sigma/mu/w into log2-domain pm; zero ST replicas + misc.
// ---------------------------------------------------------------------------
__global__ __launch_bounds__(512) void k_prep(
    const float* __restrict__ mu, const float* __restrict__ w,
    const float* __restrict__ sigma, float* __restrict__ ws) {
  const int t = threadIdx.x;  // component id
  const float sg = sigma[0];
  const float k = LOG2E / (2.0f * sg * sg);
  const float m0 = mu[3 * t], m1 = mu[3 * t + 1], m2 = mu[3 * t + 2];
  float4* pm = (float4*)(ws + PM4_OFF);
  pm[t] = make_float4(2.0f * k * m0, 2.0f * k * m1, 2.0f * k * m2,
                      LOG2E * w[t] - (m0 * m0 + m1 * m1 + m2 * m2) * k);
  float* ST = ws + ST_OFF;
#pragma unroll
  for (int r = 0; r < NREP * 4; ++r) ST[r * NC + t] = 0.f;
  if (t < 8) ws[MISC_OFF + t] = 0.f;
}

// ---------------------------------------------------------------------------
// E-step: block = 512 thr = 64 points x 8 comp-chunks (64 comps each).
// Phase A: per-chunk (max, sumexp2, w-moment) -> combine -> z2, glg.
// Phase C: thread owns comp t across the block's 64 points.
// ---------------------------------------------------------------------------
__global__ __launch_bounds__(512, 8) void k_estep(
    const float* __restrict__ X, float* __restrict__ ws,
    float* __restrict__ out) {
  __shared__ float4 s_pt[64];      // (x0,x1,x2,z2)
  __shared__ float4 s_ms[8][64];   // per-chunk (max, sumexp, wmom, 0)

  float* __restrict__ ST = ws + ST_OFF;
  float* __restrict__ misc = ws + MISC_OFF;
  const float4* __restrict__ pm = (const float4*)(ws + PM4_OFF);

  const int t = threadIdx.x;
  const int p = t & 63;
  const int ch = __builtin_amdgcn_readfirstlane(t >> 6);  // wave-uniform
  const int n = blockIdx.x * 64 + p;
  const float x0 = X[3 * n], x1 = X[3 * n + 1], x2 = X[3 * n + 2];

  // --- phase A: (max, sumexp2, wmom) over this chunk's 64 comps ---
  const float4* __restrict__ pmc = pm + ch * 64;
  {
    float ma = -FLT_MAX, mb = -FLT_MAX, mc = -FLT_MAX, md = -FLT_MAX;
#pragma unroll 4
    for (int i = 0; i < 64; i += 4) {
      float4 a = pmc[i], b = pmc[i + 1], c = pmc[i + 2], d = pmc[i + 3];
      ma = fmaxf(ma, fmaf(a.x, x0, fmaf(a.y, x1, fmaf(a.z, x2, a.w))));
      mb = fmaxf(mb, fmaf(b.x, x0, fmaf(b.y, x1, fmaf(b.z, x2, b.w))));
      mc = fmaxf(mc, fmaf(c.x, x0, fmaf(c.y, x1, fmaf(c.z, x2, c.w))));
      md = fmaxf(md, fmaf(d.x, x0, fmaf(d.y, x1, fmaf(d.z, x2, d.w))));
    }
    const float m = fmaxf(fmaxf(ma, mb), fmaxf(mc, md));
    float sa = 0.f, sb = 0.f, wa = 0.f, wb = 0.f;
#pragma unroll 4
    for (int i = 0; i < 64; i += 2) {
      float4 a = pmc[i], b = pmc[i + 1];
      float da = fmaf(a.x, x0, fmaf(a.y, x1, fmaf(a.z, x2, a.w))) - m;
      float db = fmaf(b.x, x0, fmaf(b.y, x1, fmaf(b.z, x2, b.w))) - m;
      float ea = fexp2(da);
      float eb = fexp2(db);
      sa += ea; wa = fmaf(ea, da, wa);
      sb += eb; wb = fmaf(eb, db, wb);
    }
    s_ms[ch][p] = make_float4(m, sa + sb, wa + wb, 0.f);
  }
  __syncthreads();

  float glg = 0.f, xx = 0.f;
  if (t < 64) {  // combine 8 chunk partials for point t (p == t)
    float M = -FLT_MAX;
    float4 q[8];
#pragma unroll
    for (int i = 0; i < 8; ++i) { q[i] = s_ms[i][t]; M = fmaxf(M, q[i].x); }
    float SS = 0.f;
    float e[8];
#pragma unroll
    for (int i = 0; i < 8; ++i) { e[i] = fexp2(q[i].x - M); SS += e[i] * q[i].y; }
    const float z2 = M + flog2(SS);
    float gnum = 0.f;
#pragma unroll
    for (int i = 0; i < 8; ++i) gnum += e[i] * fmaf(q[i].x - z2, q[i].y, q[i].z);
    glg = gnum / SS;  // sum_c gamma*(l2 - z2), log2 units
    xx = x0 * x0 + x1 * x1 + x2 * x2;
    s_pt[t] = make_float4(x0, x1, x2, z2);
    out[3 * n] = z2;  // staged for k_final
  }
  // wave 0 only carries glg/xx — reduce within wave 0, no LDS needed
  {
    float rl = waveSum(glg);
    float rx = waveSum(xx);
    if (t == 0) { atomicAdd(&misc[0], rx); atomicAdd(&misc[3], rl); }
  }
  __syncthreads();  // publish s_pt

  // --- phase C: thread t owns comp t across the block's 64 points ---
  {
    const float4 pc = pm[t];
    float Sg = 0.f, Tx = 0.f, Ty = 0.f, Tz = 0.f;
#pragma unroll 4
    for (int i = 0; i < 64; ++i) {
      float4 pt = s_pt[i];  // broadcast read
      float l = fmaf(pc.x, pt.x, fmaf(pc.y, pt.y, fmaf(pc.z, pt.z, pc.w)));
      float g = fexp2(l - pt.w);
      Sg += g;
      Tx = fmaf(g, pt.x, Tx);
      Ty = fmaf(g, pt.y, Ty);
      Tz = fmaf(g, pt.z, Tz);
    }
    float* st = ST + (((blockIdx.x & (NREP - 1)) * NC + t) << 2);
    atomicAdd(st + 0, Tx);
    atomicAdd(st + 1, Ty);
    atomicAdd(st + 2, Tz);
    atomicAdd(st + 3, Sg);
  }
}

// ---------------------------------------------------------------------------
// M-step: one block, 512 threads (one per component). Sums ST replicas.
// gd = sum|x|^2 + sum_c (S_c|mu_c|^2 - 2 mu_c.T_c);  logpi = h - lse(h).
// Seeds Cfe: sum_c S_c A_c + LN2*sum(gamma lg2gamma) + N*d*ln(sigma_new).
// ---------------------------------------------------------------------------
__global__ __launch_bounds__(512) void k_mstep(
    const float* __restrict__ mu, float* __restrict__ ws,
    float* __restrict__ out) {
  __shared__ float s_red[8];
  __shared__ float s_red2[8];
  __shared__ float s_bc[4];
  const int t = threadIdx.x;
  const float4* __restrict__ ST4 = (const float4*)(ws + ST_OFF);
  float* __restrict__ misc = ws + MISC_OFF;

  float Tx = 0.f, Ty = 0.f, Tz = 0.f, S = 0.f;
#pragma unroll
  for (int r = 0; r < NREP; ++r) {
    float4 v = ST4[r * NC + t];
    Tx += v.x; Ty += v.y; Tz += v.z; S += v.w;
  }
  const float Sc = fmaxf(S, 1e-30f);
  const float h2 = flog2(Sc);
  const float m0 = Tx / Sc, m1 = Ty / Sc, m2 = Tz / Sc;
  const float o0 = mu[3 * t], o1 = mu[3 * t + 1], o2 = mu[3 * t + 2];
  const float gdp = S * (o0 * o0 + o1 * o1 + o2 * o2)
                    - 2.0f * (o0 * Tx + o1 * Ty + o2 * Tz);

  float hm = waveMax(h2);
  if ((t & 63) == 0) s_red[t >> 6] = hm;
  __syncthreads();
  if (t == 0) {
    float v = s_red[0];
    for (int i = 1; i < 8; ++i) v = fmaxf(v, s_red[i]);
    s_bc[0] = v;
  }
  __syncthreads();
  const float hM = s_bc[0];
  float es = waveSum(fexp2(h2 - hM));
  float gs = waveSum(gdp);
  if ((t & 63) == 0) { s_red[t >> 6] = es; s_red2[t >> 6] = gs; }
  __syncthreads();
  if (t == 0) {
    float esum = 0.f, gsum = 0.f;
    for (int i = 0; i < 8; ++i) { esum += s_red[i]; gsum += s_red2[i]; }
    s_bc[1] = hM + flog2(esum);                            // lse2(h2)
    const float gd = fmaxf(misc[0] + gsum, 1e-20f);
    const float sn2 = gd * (1.0f / (3.0f * (float)NPTS));  // sigma_new^2
    s_bc[2] = 1.0f / (2.0f * sn2);                         // inv2s2_new
    s_bc[3] = LN2 * 1.5f * flog2(sn2);                     // d*ln(sigma_new)
  }
  __syncthreads();

  const float inv2s2n = s_bc[2];
  const float logpi = LN2 * (h2 - s_bc[1]);                // ln units
  const float A = (m0 * m0 + m1 * m1 + m2 * m2) * inv2s2n - logpi;
  ((float4*)(ws + PQ4_OFF))[t] = make_float4(m0, m1, m2, A);

  // Cfe seed: sum_c S_c*A_c + LN2*glg_total + N*d*ln(sigma_new)
  float rs = waveSum(S * A);
  if ((t & 63) == 0) s_red[t >> 6] = rs;
  __syncthreads();
  if (t == 0) {
    float v = 0.f;
    for (int i = 0; i < 8; ++i) v += s_red[i];
    out[NPTS * 3] = v + LN2 * misc[3] + (float)NPTS * s_bc[3];
    misc[1] = inv2s2n;
  }
}

// ---------------------------------------------------------------------------
// Final: block = 512 thr = 64 points x 8 chunks. Y = gamma @ mu_new;
// per-point Cfe contribution is -|Y|^2 * inv2s2n (rest seeded in k_mstep).
// ---------------------------------------------------------------------------
__global__ __launch_bounds__(512, 8) void k_final(
    const float* __restrict__ X, const float* __restrict__ ws,
    float* __restrict__ out) {
  __shared__ float4 s_y[8][64];

  const float4* __restrict__ pm = (const float4*)(ws + PM4_OFF);
  const float4* __restrict__ pq = (const float4*)(ws + PQ4_OFF);
  const float* __restrict__ misc = ws + MISC_OFF;

  const int t = threadIdx.x;
  const int p = t & 63;
  const int ch = __builtin_amdgcn_readfirstlane(t >> 6);
  const int n = blockIdx.x * 64 + p;
  const float x0 = X[3 * n], x1 = X[3 * n + 1], x2 = X[3 * n + 2];
  const float z2 = out[3 * n];  // staged by k_estep; overwritten after barrier
  const float inv2s2n = misc[1];

  const float4* __restrict__ pmc = pm + ch * 64;
  const float4* __restrict__ pqc = pq + ch * 64;
  float y0 = 0.f, y1 = 0.f, y2 = 0.f;
#pragma unroll 4
  for (int i = 0; i < 64; ++i) {
    float4 pp = pmc[i];
    float4 qq = pqc[i];
    float l = fmaf(pp.x, x0, fmaf(pp.y, x1, fmaf(pp.z, x2, pp.w))) - z2;
    float g = fexp2(l);
    y0 = fmaf(g, qq.x, y0);
    y1 = fmaf(g, qq.y, y1);
    y2 = fmaf(g, qq.z, y2);
  }
  s_y[ch][p] = make_float4(y0, y1, y2, 0.f);
  __syncthreads();

  float cfe = 0.f;
  if (t < 64) {
    float Y0 = 0.f, Y1 = 0.f, Y2 = 0.f;
#pragma unroll
    for (int i = 0; i < 8; ++i) {
      float4 a = s_y[i][t];
      Y0 += a.x; Y1 += a.y; Y2 += a.z;
    }
    cfe = -(Y0 * Y0 + Y1 * Y1 + Y2 * Y2) * inv2s2n;
    out[3 * n] = Y0;
    out[3 * n + 1] = Y1;
    out[3 * n + 2] = Y2;
  }
  // wave 0 only carries cfe — reduce within wave 0
  float r = waveSum(cfe);
  if (t == 0) atomicAdd(&out[NPTS * 3], r);
}

extern "C" void kernel_launch(void* const* d_in, const int* in_sizes, int n_in,
                              void* d_out, int out_size, void* d_ws, size_t ws_size,
                              hipStream_t stream) {
  const float* X = (const float*)d_in[0];
  const float* mu = (const float*)d_in[1];
  const float* w = (const float*)d_in[2];
  const float* sigma = (const float*)d_in[3];
  float* out = (float*)d_out;
  float* ws = (float*)d_ws;

  k_prep<<<1, 512, 0, stream>>>(mu, w, sigma, ws);
  k_estep<<<NPTS / 64, 512, 0, stream>>>(X, ws, out);
  k_mstep<<<1, 512, 0, stream>>>(mu, ws, out);
  k_final<<<NPTS / 64, 512, 0, stream>>>(X, ws, out);
}

// Round 8
// 180.384 us; speedup vs baseline: 1.0680x; 1.0680x over previous
//
#include <hip/hip_runtime.h>
#include <cfloat>
#include <cmath>

#define NPTS 131072
#define NC   512
#define NREP 4
#define LOG2E 1.44269504088896340736f
#define LN2   0.69314718055994530942f

typedef float v2f __attribute__((ext_vector_type(2)));

// v_exp_f32 computes 2^x; v_log_f32 computes log2(x). Raw builtins avoid the
// glibc __exp2f/__log2f macro collision (R5 compile failure).
__device__ __forceinline__ float fexp2(float x) { return __builtin_amdgcn_exp2f(x); }
__device__ __forceinline__ float flog2(float x) { return __builtin_amdgcn_logf(x); }
__device__ __forceinline__ v2f pkfma(v2f a, v2f b, v2f c) {
  return __builtin_elementwise_fma(a, b, c);
}
__device__ __forceinline__ v2f sp(float s) { return (v2f){s, s}; }

// ws float-index layout:
//  PM4  [0, 2048)      : per-comp float4 LOG2-domain (2k*mu, log2e*w-|mu|^2 k), k=log2e/(2s^2)
//  PMP  [2048, 4096)   : 256 comp-pairs x 8 floats {x0,x1,y0,y1,z0,z1,w0,w1}
//  PMQP [4096, 8192)   : 256 comp-pairs x 16 floats {pm 8 | qx0,qx1,qy0,qy1,qz0,qz1,pad,pad}
//  ST   [8192, 16384)  : NREP replicas x 512 comps x float4 (Tx,Ty,Tz,S)
//  MISC [16384, 16392) : [0]=sum|x|^2, [1]=inv2s2_new, [3]=sum gamma*lg2gamma
// z_n staged in d_out[3n] (k_estep writes, k_final reads then overwrites).
#define PM4_OFF  0
#define PMP_OFF  2048
#define PMQP_OFF 4096
#define ST_OFF   8192
#define MISC_OFF 16384

__device__ __forceinline__ float waveSum(float v) {
#pragma unroll
  for (int off = 32; off > 0; off >>= 1) v += __shfl_down(v, off, 64);
  return v;
}
__device__ __forceinline__ float waveMax(float v) {
#pragma unroll
  for (int off = 32; off > 0; off >>= 1) v = fmaxf(v, __shfl_down(v, off, 64));
  return v;
}

// ---------------------------------------------------------------------------
// Prep: fold sigma/mu/w into log2-domain pm (AoS + pair-interleaved copies);
// zero ST replicas + misc.
// ---------------------------------------------------------------------------
__global__ __launch_bounds__(512) void k_prep(
    const float* __restrict__ mu, const float* __restrict__ w,
    const float* __restrict__ sigma, float* __restrict__ ws) {
  const int t = threadIdx.x;  // component id
  const float sg = sigma[0];
  const float k = LOG2E / (2.0f * sg * sg);
  const float m0 = mu[3 * t], m1 = mu[3 * t + 1], m2 = mu[3 * t + 2];
  const float px = 2.0f * k * m0, py = 2.0f * k * m1, pz = 2.0f * k * m2;
  const float pw = LOG2E * w[t] - (m0 * m0 + m1 * m1 + m2 * m2) * k;
  ((float4*)(ws + PM4_OFF))[t] = make_float4(px, py, pz, pw);
  const int j = t >> 1, b = t & 1;
  float* pmp = ws + PMP_OFF + 8 * j;
  pmp[0 + b] = px; pmp[2 + b] = py; pmp[4 + b] = pz; pmp[6 + b] = pw;
  float* pmq = ws + PMQP_OFF + 16 * j;
  pmq[0 + b] = px; pmq[2 + b] = py; pmq[4 + b] = pz; pmq[6 + b] = pw;
  float* ST = ws + ST_OFF;
#pragma unroll
  for (int r = 0; r < NREP * 4; ++r) ST[r * NC + t] = 0.f;
  if (t < 8) ws[MISC_OFF + t] = 0.f;
}

// ---------------------------------------------------------------------------
// E-step: block = 512 thr = 128 points x 4 comp-chunks (64 comp-pairs each).
// Phase A: packed (max, sumexp2, wmom) per chunk -> combine -> z2, glg.
// Phase C: thread owns comp t over 64 point-pairs (SoA LDS, packed).
// ---------------------------------------------------------------------------
__global__ __launch_bounds__(512, 8) void k_estep(
    const float* __restrict__ X, float* __restrict__ ws,
    float* __restrict__ out) {
  __shared__ float4 s_ms[4][128];  // per-chunk (max, sumexp, wmom, 0)
  __shared__ v2f s_x2[64], s_y2[64], s_z2[64], s_zz[64];  // point-pair SoA

  float* __restrict__ ST = ws + ST_OFF;
  float* __restrict__ misc = ws + MISC_OFF;

  const int t = threadIdx.x;
  const int p = t & 127;
  const int ch = __builtin_amdgcn_readfirstlane(t >> 7);  // wave-uniform
  const int n = blockIdx.x * 128 + p;
  const float x0 = X[3 * n], x1 = X[3 * n + 1], x2 = X[3 * n + 2];
  const v2f x0v = sp(x0), x1v = sp(x1), x2v = sp(x2);

  // --- phase A over this chunk's 64 comp-pairs (pair-interleaved, packed) ---
  const v2f* __restrict__ pmp = (const v2f*)(ws + PMP_OFF) + 256 * ch;
  {
    v2f mm = sp(-FLT_MAX);
#pragma unroll 4
    for (int j = 0; j < 64; ++j) {
      const v2f* r = pmp + 4 * j;
      v2f l = pkfma(r[0], x0v, pkfma(r[1], x1v, pkfma(r[2], x2v, r[3])));
      mm.x = fmaxf(mm.x, l.x);
      mm.y = fmaxf(mm.y, l.y);
    }
    const float m = fmaxf(mm.x, mm.y);
    const v2f mv = sp(m);
    v2f sa = sp(0.f), wa = sp(0.f);
#pragma unroll 4
    for (int j = 0; j < 64; ++j) {
      const v2f* r = pmp + 4 * j;
      v2f l = pkfma(r[0], x0v, pkfma(r[1], x1v, pkfma(r[2], x2v, r[3])));
      v2f d = l - mv;
      v2f e = (v2f){fexp2(d.x), fexp2(d.y)};
      sa += e;
      wa = pkfma(e, d, wa);
    }
    s_ms[ch][p] = make_float4(m, sa.x + sa.y, wa.x + wa.y, 0.f);
  }
  __syncthreads();

  if (t < 128) {  // combine 4 chunk partials for point t
    float4 q0 = s_ms[0][t], q1 = s_ms[1][t], q2 = s_ms[2][t], q3 = s_ms[3][t];
    float M = fmaxf(fmaxf(q0.x, q1.x), fmaxf(q2.x, q3.x));
    float e0 = fexp2(q0.x - M), e1 = fexp2(q1.x - M);
    float e2 = fexp2(q2.x - M), e3 = fexp2(q3.x - M);
    float SS = e0 * q0.y + e1 * q1.y + e2 * q2.y + e3 * q3.y;
    float z2 = M + flog2(SS);
    float gnum = e0 * fmaf(q0.x - z2, q0.y, q0.z) + e1 * fmaf(q1.x - z2, q1.y, q1.z) +
                 e2 * fmaf(q2.x - z2, q2.y, q2.z) + e3 * fmaf(q3.x - z2, q3.y, q3.z);
    float glg = gnum / SS;  // sum_c gamma*(l2 - z2), log2 units
    float xx = x0 * x0 + x1 * x1 + x2 * x2;
    ((float*)s_x2)[t] = x0;
    ((float*)s_y2)[t] = x1;
    ((float*)s_z2)[t] = x2;
    ((float*)s_zz)[t] = z2;
    out[3 * n] = z2;  // staged for k_final
    // waves 0,1 reduce glg/xx directly (both fully active for t<128)
    float rl = waveSum(glg);
    float rx = waveSum(xx);
    if ((t & 63) == 0) {
      atomicAdd(&misc[0], rx);
      atomicAdd(&misc[3], rl);
    }
  }
  __syncthreads();  // publish SoA point data

  // --- phase C: thread t owns comp t across 64 point-pairs (packed) ---
  {
    const float4 pc = ((const float4*)(ws + PM4_OFF))[t];
    const v2f pcx = sp(pc.x), pcy = sp(pc.y), pcz = sp(pc.z), pcw = sp(pc.w);
    v2f Sg = sp(0.f), Tx = sp(0.f), Ty = sp(0.f), Tz = sp(0.f);
#pragma unroll 4
    for (int i = 0; i < 64; ++i) {
      v2f xp = s_x2[i], yp = s_y2[i], zp = s_z2[i], zz = s_zz[i];
      v2f l = pkfma(xp, pcx, pkfma(yp, pcy, pkfma(zp, pcz, pcw)));
      v2f d = l - zz;
      v2f g = (v2f){fexp2(d.x), fexp2(d.y)};
      Sg += g;
      Tx = pkfma(g, xp, Tx);
      Ty = pkfma(g, yp, Ty);
      Tz = pkfma(g, zp, Tz);
    }
    float* st = ST + (((blockIdx.x & (NREP - 1)) * NC + t) << 2);
    atomicAdd(st + 0, Tx.x + Tx.y);
    atomicAdd(st + 1, Ty.x + Ty.y);
    atomicAdd(st + 2, Tz.x + Tz.y);
    atomicAdd(st + 3, Sg.x + Sg.y);
  }
}

// ---------------------------------------------------------------------------
// M-step: one block, 512 threads (one per component). Sums ST replicas.
// gd = sum|x|^2 + sum_c (S_c|mu_c|^2 - 2 mu_c.T_c);  logpi = h - lse(h).
// Writes mu_new into PMQP pair records; seeds Cfe into out[N*3].
// ---------------------------------------------------------------------------
__global__ __launch_bounds__(512) void k_mstep(
    const float* __restrict__ mu, float* __restrict__ ws,
    float* __restrict__ out) {
  __shared__ float s_red[8];
  __shared__ float s_red2[8];
  __shared__ float s_bc[4];
  const int t = threadIdx.x;
  const float4* __restrict__ ST4 = (const float4*)(ws + ST_OFF);
  float* __restrict__ misc = ws + MISC_OFF;

  float Tx = 0.f, Ty = 0.f, Tz = 0.f, S = 0.f;
#pragma unroll
  for (int r = 0; r < NREP; ++r) {
    float4 v = ST4[r * NC + t];
    Tx += v.x; Ty += v.y; Tz += v.z; S += v.w;
  }
  const float Sc = fmaxf(S, 1e-30f);
  const float h2 = flog2(Sc);
  const float m0 = Tx / Sc, m1 = Ty / Sc, m2 = Tz / Sc;
  const float o0 = mu[3 * t], o1 = mu[3 * t + 1], o2 = mu[3 * t + 2];
  const float gdp = S * (o0 * o0 + o1 * o1 + o2 * o2)
                    - 2.0f * (o0 * Tx + o1 * Ty + o2 * Tz);

  float hm = waveMax(h2);
  if ((t & 63) == 0) s_red[t >> 6] = hm;
  __syncthreads();
  if (t == 0) {
    float v = s_red[0];
    for (int i = 1; i < 8; ++i) v = fmaxf(v, s_red[i]);
    s_bc[0] = v;
  }
  __syncthreads();
  const float hM = s_bc[0];
  float es = waveSum(fexp2(h2 - hM));
  float gs = waveSum(gdp);
  if ((t & 63) == 0) { s_red[t >> 6] = es; s_red2[t >> 6] = gs; }
  __syncthreads();
  if (t == 0) {
    float esum = 0.f, gsum = 0.f;
    for (int i = 0; i < 8; ++i) { esum += s_red[i]; gsum += s_red2[i]; }
    s_bc[1] = hM + flog2(esum);                            // lse2(h2)
    const float gd = fmaxf(misc[0] + gsum, 1e-20f);
    const float sn2 = gd * (1.0f / (3.0f * (float)NPTS));  // sigma_new^2
    s_bc[2] = 1.0f / (2.0f * sn2);                         // inv2s2_new
    s_bc[3] = LN2 * 1.5f * flog2(sn2);                     // d*ln(sigma_new)
  }
  __syncthreads();

  const float inv2s2n = s_bc[2];
  const float logpi = LN2 * (h2 - s_bc[1]);                // ln units
  const float A = (m0 * m0 + m1 * m1 + m2 * m2) * inv2s2n - logpi;

  // mu_new into PMQP pair record (q-part)
  float* q = ws + PMQP_OFF + 16 * (t >> 1) + 8 + (t & 1);
  q[0] = m0; q[2] = m1; q[4] = m2;

  // Cfe seed: sum_c S_c*A_c + LN2*glg_total + N*d*ln(sigma_new)
  float rs = waveSum(S * A);
  if ((t & 63) == 0) s_red[t >> 6] = rs;
  __syncthreads();
  if (t == 0) {
    float v = 0.f;
    for (int i = 0; i < 8; ++i) v += s_red[i];
    out[NPTS * 3] = v + LN2 * misc[3] + (float)NPTS * s_bc[3];
    misc[1] = inv2s2n;
  }
}

// ---------------------------------------------------------------------------
// Final: block = 512 thr = 128 points x 4 chunks (64 comp-pairs each, packed).
// Y = gamma @ mu_new; per-point Cfe contribution -|Y|^2 * inv2s2n.
// ---------------------------------------------------------------------------
__global__ __launch_bounds__(512, 8) void k_final(
    const float* __restrict__ X, const float* __restrict__ ws,
    float* __restrict__ out) {
  __shared__ float4 s_y[4][128];

  const float* __restrict__ misc = ws + MISC_OFF;
  const int t = threadIdx.x;
  const int p = t & 127;
  const int ch = __builtin_amdgcn_readfirstlane(t >> 7);
  const int n = blockIdx.x * 128 + p;
  const float x0 = X[3 * n], x1 = X[3 * n + 1], x2 = X[3 * n + 2];
  const float z2 = out[3 * n];  // staged by k_estep; overwritten after barrier
  const float inv2s2n = misc[1];
  const v2f x0v = sp(x0), x1v = sp(x1), x2v = sp(x2), zv = sp(z2);

  const v2f* __restrict__ pmq = (const v2f*)(ws + PMQP_OFF) + 512 * ch;
  v2f yx = sp(0.f), yy = sp(0.f), yz = sp(0.f);
#pragma unroll 4
  for (int j = 0; j < 64; ++j) {
    const v2f* r = pmq + 8 * j;
    v2f l = pkfma(r[0], x0v, pkfma(r[1], x1v, pkfma(r[2], x2v, r[3])));
    v2f d = l - zv;
    v2f g = (v2f){fexp2(d.x), fexp2(d.y)};
    yx = pkfma(g, r[4], yx);
    yy = pkfma(g, r[5], yy);
    yz = pkfma(g, r[6], yz);
  }
  s_y[ch][p] = make_float4(yx.x + yx.y, yy.x + yy.y, yz.x + yz.y, 0.f);
  __syncthreads();

  if (t < 128) {
    float4 a0 = s_y[0][t], a1 = s_y[1][t], a2 = s_y[2][t], a3 = s_y[3][t];
    float Y0 = (a0.x + a1.x) + (a2.x + a3.x);
    float Y1 = (a0.y + a1.y) + (a2.y + a3.y);
    float Y2 = (a0.z + a1.z) + (a2.z + a3.z);
    float cfe = -(Y0 * Y0 + Y1 * Y1 + Y2 * Y2) * inv2s2n;
    out[3 * n] = Y0;
    out[3 * n + 1] = Y1;
    out[3 * n + 2] = Y2;
    float r = waveSum(cfe);  // waves 0,1 fully active for t<128
    if ((t & 63) == 0) atomicAdd(&out[NPTS * 3], r);
  }
}

extern "C" void kernel_launch(void* const* d_in, const int* in_sizes, int n_in,
                              void* d_out, int out_size, void* d_ws, size_t ws_size,
                              hipStream_t stream) {
  const float* X = (const float*)d_in[0];
  const float* mu = (const float*)d_in[1];
  const float* w = (const float*)d_in[2];
  const float* sigma = (const float*)d_in[3];
  float* out = (float*)d_out;
  float* ws = (float*)d_ws;

  k_prep<<<1, 512, 0, stream>>>(mu, w, sigma, ws);
  k_estep<<<NPTS / 128, 512, 0, stream>>>(X, ws, out);
  k_mstep<<<1, 512, 0, stream>>>(mu, ws, out);
  k_final<<<NPTS / 128, 512, 0, stream>>>(X, ws, out);
}